// Round 2
// 242.045 us; speedup vs baseline: 1.1456x; 1.1456x over previous
//
#include <hip/hip_runtime.h>
#include <float.h>

#define DECAY 0.1f
#define OMD   0.9f
#define EPS   1e-5f
#define NORM_EPS 1e-8f

static constexpr int D = 32;

typedef __attribute__((ext_vector_type(8))) short s16x8;
typedef __attribute__((ext_vector_type(4))) float f32x4_t;

__device__ __forceinline__ float bf2f(short s) {
    return __uint_as_float(((unsigned int)(unsigned short)s) << 16);
}

struct Split3 { short b0, b1, b2; };

// Exact 3-way bf16 truncation split: v == b0 + b1 + b2 (fp32 mantissa = 24 bits = 3x8).
__device__ __forceinline__ Split3 split3(float v) {
    const unsigned int u0 = __float_as_uint(v) & 0xFFFF0000u;
    const float r  = v - __uint_as_float(u0);
    const unsigned int u1 = __float_as_uint(r) & 0xFFFF0000u;
    const float r2 = r - __uint_as_float(u1);
    Split3 s;
    s.b0 = (short)(u0 >> 16);
    s.b1 = (short)(u1 >> 16);
    s.b2 = (short)(__float_as_uint(r2) >> 16);
    return s;
}

// ---------------- K1: normalize codebook + split into MFMA B-fragment layout ----
// B-frag layout per 16-code tile: [plane 0..2][lane 0..63][8 bf16] (3072 B/tile).
// Lane l holds B[k=(l>>4)*8+i][col=l&15] where B[k][col] = 2*en[tile*16+col][k].
// negE2[k] = -|en_k|^2  (folded into MFMA C-init so score = 2*fn.en - |en|^2).
__global__ void prep_codebook(const float* __restrict__ embed,
                              unsigned short* __restrict__ bfrag,
                              float* __restrict__ negE2, int K) {
    const int k = blockIdx.x * blockDim.x + threadIdx.x;
    if (k >= K) return;
    float v[D]; float ssq = 0.f;
#pragma unroll
    for (int d = 0; d < D; ++d) { v[d] = embed[(size_t)k * D + d]; ssq += v[d] * v[d]; }
    const float inv = 1.0f / (sqrtf(ssq) + NORM_EPS);
    float e2 = 0.f;
    short p0[D], p1[D], p2[D];
#pragma unroll
    for (int d = 0; d < D; ++d) {
        const float e = v[d] * inv;
        e2 += e * e;
        const Split3 s = split3(2.0f * e);   // fold the *2 into the splits (exact)
        p0[d] = s.b0; p1[d] = s.b1; p2[d] = s.b2;
    }
    negE2[k] = -e2;
    unsigned short* base = bfrag + (size_t)(k >> 4) * 1536;   // tile base, in shorts
    const int col = k & 15;
#pragma unroll
    for (int g = 0; g < 4; ++g) {                 // k-chunk g -> lane g*16+col
        const int lid = g * 16 + col;
        s16x8 s0, s1, s2;
#pragma unroll
        for (int i = 0; i < 8; ++i) { s0[i] = p0[g*8+i]; s1[i] = p1[g*8+i]; s2[i] = p2[g*8+i]; }
        *(s16x8*)(base + 0*512 + lid*8) = s0;
        *(s16x8*)(base + 1*512 + lid*8) = s1;
        *(s16x8*)(base + 2*512 + lid*8) = s2;
    }
}

// ---------------- K2: MFMA assignment + quantize + scatter stats ----------------
// 256 thr = 4 waves, 128 points/block (32/wave = 2 x 16-point groups).
// Score GEMM via 8-product bf16x3 (drop only a2*b2 <= 2^-30): fp32-class precision.
__global__ __launch_bounds__(256)
void assign_kernel(const float* __restrict__ x,
                   const unsigned short* __restrict__ bfrag,
                   const float* __restrict__ negE2,
                   float* __restrict__ out_quant,
                   float* __restrict__ out_ind,
                   float* __restrict__ bins,
                   float* __restrict__ esum,
                   int N, int K) {
    constexpr int PB = 128;
    __shared__ char sm[49152];          // phase1: A-frags (24KB). loop: 2 x 24KB B dbuf
    __shared__ int  best_c[PB];

    const int tid  = threadIdx.x;
    const int lane = tid & 63;
    const int w    = tid >> 6;
    const int n0   = blockIdx.x * PB;
    const int col  = lane & 15;

    float fn_r[16];
    // ---- phase 1: load + normalize + exact split into A-fragment LDS ----
    {
        const int p = tid >> 1, h = tid & 1;     // 2 threads per point
        const float* xp = &x[(size_t)(n0 + p) * D + h * 16];
        const float4 va = *(const float4*)(xp);
        const float4 vb = *(const float4*)(xp + 4);
        const float4 vc = *(const float4*)(xp + 8);
        const float4 vd = *(const float4*)(xp + 12);
        float ssq = va.x*va.x + va.y*va.y + va.z*va.z + va.w*va.w
                  + vb.x*vb.x + vb.y*vb.y + vb.z*vb.z + vb.w*vb.w
                  + vc.x*vc.x + vc.y*vc.y + vc.z*vc.z + vc.w*vc.w
                  + vd.x*vd.x + vd.y*vd.y + vd.z*vd.z + vd.w*vd.w;
        ssq += __shfl_xor(ssq, 1);
        const float inv = 1.0f / (sqrtf(ssq) + NORM_EPS);
        fn_r[0]=va.x*inv;  fn_r[1]=va.y*inv;  fn_r[2]=va.z*inv;  fn_r[3]=va.w*inv;
        fn_r[4]=vb.x*inv;  fn_r[5]=vb.y*inv;  fn_r[6]=vb.z*inv;  fn_r[7]=vb.w*inv;
        fn_r[8]=vc.x*inv;  fn_r[9]=vc.y*inv;  fn_r[10]=vc.z*inv; fn_r[11]=vc.w*inv;
        fn_r[12]=vd.x*inv; fn_r[13]=vd.y*inv; fn_r[14]=vd.z*inv; fn_r[15]=vd.w*inv;
        // A-frag: group g=p>>4, chunk c=2h(+1) -> lane c*16+(p&15), planes stride 1024B
        char* dst = &sm[(p >> 4) * 3072 + h * 512 + (p & 15) * 16];
        {
            s16x8 s0, s1, s2;
#pragma unroll
            for (int i = 0; i < 8; ++i) {
                const Split3 s = split3(fn_r[i]);
                s0[i] = s.b0; s1[i] = s.b1; s2[i] = s.b2;
            }
            *(s16x8*)(dst) = s0; *(s16x8*)(dst + 1024) = s1; *(s16x8*)(dst + 2048) = s2;
        }
        {
            s16x8 s0, s1, s2;
#pragma unroll
            for (int i = 0; i < 8; ++i) {
                const Split3 s = split3(fn_r[8 + i]);
                s0[i] = s.b0; s1[i] = s.b1; s2[i] = s.b2;
            }
            *(s16x8*)(dst + 256) = s0; *(s16x8*)(dst + 256 + 1024) = s1; *(s16x8*)(dst + 256 + 2048) = s2;
        }
    }
    __syncthreads();

    // ---- A fragments to registers: 2 point-groups x 3 planes ----
    s16x8 A[2][3];
#pragma unroll
    for (int pg = 0; pg < 2; ++pg) {
        const int g = w * 2 + pg;
#pragma unroll
        for (int pl = 0; pl < 3; ++pl)
            A[pg][pl] = *(const s16x8*)&sm[g * 3072 + pl * 1024 + lane * 16];
    }
    __syncthreads();   // all A-reads done before staging overwrites sm

    // stage one group (8 tiles = 24KB) via global_load_lds(16B), linear dst
    auto stage = [&](int grp, int buf) {
        const char* gsrc = (const char*)bfrag + (size_t)grp * 24576 + tid * 16;
        char* ldst = &sm[buf * 24576 + w * 1024];   // wave-uniform base (+lane*16 by HW)
#pragma unroll
        for (int j = 0; j < 6; ++j) {
            __builtin_amdgcn_global_load_lds(
                (const __attribute__((address_space(1))) unsigned int*)(gsrc + j * 4096),
                (__attribute__((address_space(3))) unsigned int*)(ldst + j * 4096),
                16, 0, 0);
        }
    };

    float bestS[2][4], bestC[2][4];
#pragma unroll
    for (int pg = 0; pg < 2; ++pg)
#pragma unroll
        for (int r = 0; r < 4; ++r) { bestS[pg][r] = -1e30f; bestC[pg][r] = 0.f; }

    stage(0, 0);
    float ne2 = negE2[col];          // tile 0 prefetch
    __syncthreads();

    const int NG = K >> 7;           // groups of 128 codes (8 tiles)
    const int NT = K >> 4;           // total 16-code tiles
    for (int grp = 0; grp < NG; ++grp) {
        if (grp + 1 < NG) stage(grp + 1, (grp + 1) & 1);
        const char* bufp = &sm[(grp & 1) * 24576];
#pragma unroll
        for (int t = 0; t < 8; ++t) {
            const s16x8 B0 = *(const s16x8*)&bufp[t * 3072 +    0 + lane * 16];
            const s16x8 B1 = *(const s16x8*)&bufp[t * 3072 + 1024 + lane * 16];
            const s16x8 B2 = *(const s16x8*)&bufp[t * 3072 + 2048 + lane * 16];
            const float ne2c = ne2;
            int ntile = grp * 8 + t + 1; if (ntile >= NT) ntile = NT - 1;
            ne2 = negE2[ntile * 16 + col];                    // prefetch next tile
            const float codef = (float)(grp * 128 + t * 16 + col);
            const f32x4_t initX = {ne2c, ne2c, ne2c, ne2c};   // -|en|^2 folded into C
            const f32x4_t zero  = {0.f, 0.f, 0.f, 0.f};
#pragma unroll
            for (int pg = 0; pg < 2; ++pg) {
                // 8 of 9 split products across two independent chains (ILP)
                f32x4_t X = __builtin_amdgcn_mfma_f32_16x16x32_bf16(A[pg][0], B0, initX, 0, 0, 0);
                f32x4_t Y = __builtin_amdgcn_mfma_f32_16x16x32_bf16(A[pg][0], B1, zero,  0, 0, 0);
                X = __builtin_amdgcn_mfma_f32_16x16x32_bf16(A[pg][1], B1, X, 0, 0, 0);
                Y = __builtin_amdgcn_mfma_f32_16x16x32_bf16(A[pg][1], B0, Y, 0, 0, 0);
                X = __builtin_amdgcn_mfma_f32_16x16x32_bf16(A[pg][0], B2, X, 0, 0, 0);
                Y = __builtin_amdgcn_mfma_f32_16x16x32_bf16(A[pg][2], B0, Y, 0, 0, 0);
                X = __builtin_amdgcn_mfma_f32_16x16x32_bf16(A[pg][1], B2, X, 0, 0, 0);
                Y = __builtin_amdgcn_mfma_f32_16x16x32_bf16(A[pg][2], B1, Y, 0, 0, 0);
#pragma unroll
                for (int r = 0; r < 4; ++r) {
                    const float s = X[r] + Y[r];
                    if (s > bestS[pg][r]) { bestS[pg][r] = s; bestC[pg][r] = codef; }
                }
            }
        }
        __syncthreads();
    }

    // ---- argmax reduce across the 16 code-lanes; first-max tie-break ----
#pragma unroll
    for (int pg = 0; pg < 2; ++pg)
#pragma unroll
        for (int r = 0; r < 4; ++r) {
            float s = bestS[pg][r], c = bestC[pg][r];
#pragma unroll
            for (int off = 8; off >= 1; off >>= 1) {
                const float os = __shfl_xor(s, off);
                const float oc = __shfl_xor(c, off);
                if (os > s || (os == s && oc < c)) { s = os; c = oc; }
            }
            if (col == 0) {
                const int p = w * 32 + pg * 16 + (lane >> 4) * 4 + r;  // C/D row map
                out_ind[n0 + p] = c;
                best_c[p] = (int)c;
                atomicAdd(&bins[(int)c], 1.0f);
            }
        }
    __syncthreads();

    // ---- quantize gather (exact en = 0.5*(b0+b1+b2)) + embed_sum scatter ----
    {
        const int p = tid >> 1, h = tid & 1;
        const int b = best_c[p];
#pragma unroll
        for (int i = 0; i < 16; ++i)
            atomicAdd(&esum[(size_t)b * D + h * 16 + i], fn_r[i]);
        const unsigned short* bp = bfrag + (size_t)(b >> 4) * 1536;
#pragma unroll
        for (int cc = 0; cc < 2; ++cc) {
            const int c   = 2 * h + cc;
            const int lid = c * 16 + (b & 15);
            const s16x8 s0 = *(const s16x8*)(bp + 0*512 + lid*8);
            const s16x8 s1 = *(const s16x8*)(bp + 1*512 + lid*8);
            const s16x8 s2 = *(const s16x8*)(bp + 2*512 + lid*8);
            float o[8];
#pragma unroll
            for (int i = 0; i < 8; ++i)
                o[i] = 0.5f * ((bf2f(s0[i]) + bf2f(s1[i])) + bf2f(s2[i]));   // exact
            float4 q0 = {o[0], o[1], o[2], o[3]};
            float4 q1 = {o[4], o[5], o[6], o[7]};
            *(float4*)&out_quant[(size_t)(n0 + p) * D + c * 8]     = q0;
            *(float4*)&out_quant[(size_t)(n0 + p) * D + c * 8 + 4] = q1;
        }
    }
}

// ---------------- K3a: cluster_size_new + n_total reduce ----------------
__global__ void reduce_kernel(const float* __restrict__ cluster_size,
                              const float* __restrict__ bins,
                              float* __restrict__ out_cs,
                              float* __restrict__ n_total, int K) {
    __shared__ float red[256];
    float s = 0.f;
    for (int k = threadIdx.x; k < K; k += 256) {
        const float v = cluster_size[k] * DECAY + bins[k] * OMD;
        out_cs[k] = v;
        s += v;
    }
    red[threadIdx.x] = s;
    __syncthreads();
    for (int off = 128; off > 0; off >>= 1) {
        if (threadIdx.x < off) red[threadIdx.x] += red[threadIdx.x + off];
        __syncthreads();
    }
    if (threadIdx.x == 0) n_total[0] = red[0];
}

// ---------------- K3b: embed_avg_new + embed_updated ----------------
__global__ void finalize_kernel(const float* __restrict__ embed_avg,
                                const float* __restrict__ esum,
                                const float* __restrict__ out_cs,
                                const float* __restrict__ n_total,
                                float* __restrict__ out_avg,
                                float* __restrict__ out_upd,
                                int K) {
    const int i = blockIdx.x * blockDim.x + threadIdx.x;
    if (i >= K * D) return;
    const int k = i >> 5;   // D = 32
    const float avg = embed_avg[i] * DECAY + esum[i] * OMD;
    out_avg[i] = avg;
    const float nt = n_total[0];
    const float cs = out_cs[k];
    const float sm = (cs + EPS) / (nt + (float)K * EPS) * nt;
    out_upd[i] = avg / sm;
}

extern "C" void kernel_launch(void* const* d_in, const int* in_sizes, int n_in,
                              void* d_out, int out_size, void* d_ws, size_t ws_size,
                              hipStream_t stream) {
    const float* x            = (const float*)d_in[0];
    const float* embed        = (const float*)d_in[1];
    const float* cluster_size = (const float*)d_in[2];
    const float* embed_avg    = (const float*)d_in[3];

    const int KD = in_sizes[1];       // K*D = 131072
    const int K  = in_sizes[2];       // 4096
    const int N  = in_sizes[0] / D;   // 65536

    float* ws = (float*)d_ws;
    unsigned short* bfrag = (unsigned short*)ws;     // K*D*3 bf16 = 1.5*KD floats
    float* negE2 = ws + (size_t)KD * 3 / 2;          // K
    float* bins  = negE2 + K;                        // K
    float* esum  = bins + K;                         // KD
    float* ntot  = esum + KD;                        // 1   (total 1.34 MB < old 1.61 MB)

    float* out     = (float*)d_out;
    float* o_quant = out;                        // N*D
    float* o_ind   = o_quant + (size_t)N * D;    // N
    float* o_cs    = o_ind   + N;                // K
    float* o_avg   = o_cs    + K;                // KD
    float* o_upd   = o_avg   + KD;               // KD

    // zero the accumulators (bins, esum, ntot are contiguous)
    (void)hipMemsetAsync(bins, 0, (size_t)(K + KD + 1) * sizeof(float), stream);

    prep_codebook<<<(K + 63) / 64, 64, 0, stream>>>(embed, bfrag, negE2, K);
    assign_kernel<<<N / 128, 256, 0, stream>>>(x, bfrag, negE2,
                                               o_quant, o_ind, bins, esum, N, K);
    reduce_kernel<<<1, 256, 0, stream>>>(cluster_size, bins, o_cs, ntot, K);
    finalize_kernel<<<(KD + 255) / 256, 256, 0, stream>>>(embed_avg, esum, o_cs, ntot,
                                                          o_avg, o_upd, K);
}